// Round 8
// baseline (1983.328 us; speedup 1.0000x reference)
//
#include <hip/hip_runtime.h>
#include <hip/hip_bf16.h>

// DTGCN: B=16,N=256,T=64,W=12,H=64,ED=64,S=5,C=4,E=2048, FG=76
// R8: phase-A rewrite — each WG computes full XW^T via MFMA (K=96 fused
// win|h, h from packed-bf16 global mirror), df via split-bf16-A MFMA.
// XW exchange eliminated; 3 fence-free barriers/step (de, Msum/deg, h).

typedef unsigned short u16;
typedef unsigned int u32;
typedef __attribute__((ext_vector_type(8))) short bf16x8;
typedef __attribute__((ext_vector_type(4))) float f32x4;

#define B_ 16
#define N_ 256
#define T_ 64
#define W_ 12
#define S_ 5
#define E_ 2048
#define FG_ 76
#define G_ 16

__device__ __forceinline__ float b2f(u16 u) {
  union { u32 i; float f; } v; v.i = ((u32)u) << 16; return v.f;
}
__device__ __forceinline__ u16 f2b(float f) {
  union { float f; u32 i; } v; v.f = f;
  u32 x = v.i; x += 0x7fff + ((x >> 16) & 1); return (u16)(x >> 16);
}
__device__ __forceinline__ float ftanh(float x) {
  float e = __expf(-2.f * fabsf(x));
  float t = (1.f - e) / (1.f + e);
  return x < 0.f ? -t : t;
}
__device__ __forceinline__ float fsigm(float x) { return 1.f / (1.f + __expf(-x)); }
__device__ __forceinline__ float cvload(const void* p, int i, int f) {
  return f ? ((const float*)p)[i] : b2f(((const u16*)p)[i]);
}
__device__ __forceinline__ float gld(const float* p) {
  return __hip_atomic_load(p, __ATOMIC_RELAXED, __HIP_MEMORY_SCOPE_SYSTEM);
}
__device__ __forceinline__ void gst(float* p, float v) {
  __hip_atomic_store(p, v, __ATOMIC_RELAXED, __HIP_MEMORY_SCOPE_SYSTEM);
}
__device__ __forceinline__ u32 gldu(const u32* p) {
  return __hip_atomic_load(p, __ATOMIC_RELAXED, __HIP_MEMORY_SCOPE_SYSTEM);
}
__device__ __forceinline__ void gstu(u32* p, u32 v) {
  __hip_atomic_store(p, v, __ATOMIC_RELAXED, __HIP_MEMORY_SCOPE_SYSTEM);
}
__device__ __forceinline__ f32x4 mfma16(bf16x8 a, bf16x8 b, f32x4 c) {
  return __builtin_amdgcn_mfma_f32_16x16x32_bf16(a, b, c, 0, 0, 0);
}
__device__ __forceinline__ bf16x8 ldfrag(const u16* p) { return *(const bf16x8*)p; }

struct Params {
  const void *x0, *ew0, *gw0, *gb0, *w10, *b10, *w20, *b20;
  const void *wzc0, *bzc0, *wzl0, *bzl0, *wrc0, *brc0, *wrl0, *brl0;
  const void *whc0, *bhc0, *whl0, *bhl0, *clsw0, *clsb0;
  const int* eidx;
  float *xf, *ewf, *gwf, *gbf, *b1f, *b2ff;
  float *wzcf, *bzcf, *wzlf, *bzlf, *wrcf, *brcf, *wrlf, *brlf;
  float *whcf, *bhcf, *whlf, *bhlf, *clswf, *clsbf;
  u16 *w1h, *w2h;
  float *AnT, *dinvS, *uvF, *de1, *de2, *h, *Msum, *degsum, *Eh, *Ascr;
  u32 *hgp;
  int *bar, *flag;
  void* out;
};

__device__ __forceinline__ void bbar(int* ctr, int& cnt) {
  ++cnt;
  __syncthreads();
  if (threadIdx.x == 0) {
    __hip_atomic_fetch_add(ctr, 1, __ATOMIC_RELAXED, __HIP_MEMORY_SCOPE_SYSTEM);
    const int target = cnt * G_;
    while (__hip_atomic_load(ctr, __ATOMIC_RELAXED, __HIP_MEMORY_SCOPE_SYSTEM) < target)
      __builtin_amdgcn_s_sleep(1);
  }
  __syncthreads();
}

// ================= dtype detect + convert =================
__global__ void k_detect(Params p) {
  if (threadIdx.x == 0) {
    const u16* q = (const u16*)p.x0;
    int c = 0;
    for (int i = 0; i < 256; ++i) {
      int ex = (q[i] >> 7) & 0xff;
      c += (ex >= 110 && ex <= 135);
    }
    *p.flag = (c < 200) ? 1 : 0;
  }
}

__global__ void k_convert(Params p) {
  const int f = *p.flag;
  const int blk = blockIdx.x, tid = threadIdx.x;
  if (blk < 32) {
    const int base = blk * 8192;
    for (int i = tid; i < 8192; i += 256) p.xf[base + i] = cvload(p.x0, base + i, f);
    return;
  }
  if (blk == 51) { for (int i = tid; i < 4096; i += 256) p.w1h[i] = f ? f2b(((const float*)p.w10)[i]) : ((const u16*)p.w10)[i]; return; }
  if (blk == 52) { for (int i = tid; i < 4096; i += 256) p.w2h[i] = f ? f2b(((const float*)p.w20)[i]) : ((const u16*)p.w20)[i]; return; }
  const void* src = nullptr; float* dst = nullptr; int n = 0;
  switch (blk) {
    case 32: src = p.ew0;  dst = p.ewf;  n = E_;      break;
    case 33: src = p.gw0;  dst = p.gwf;  n = FG_ * 64; break;
    case 34: src = p.gb0;  dst = p.gbf;  n = 64;      break;
    case 35: src = p.b10;  dst = p.b1f;  n = 64;      break;
    case 36: src = p.b20;  dst = p.b2ff; n = 64;      break;
    case 37: src = p.wzc0; dst = p.wzcf; n = 64;      break;
    case 38: src = p.bzc0; dst = p.bzcf; n = 64;      break;
    case 39: src = p.wzl0; dst = p.wzlf; n = 8192;    break;
    case 40: src = p.bzl0; dst = p.bzlf; n = 64;      break;
    case 41: src = p.wrc0; dst = p.wrcf; n = 64;      break;
    case 42: src = p.brc0; dst = p.brcf; n = 64;      break;
    case 43: src = p.wrl0; dst = p.wrlf; n = 8192;    break;
    case 44: src = p.brl0; dst = p.brlf; n = 64;      break;
    case 45: src = p.whc0; dst = p.whcf; n = 64;      break;
    case 46: src = p.bhc0; dst = p.bhcf; n = 64;      break;
    case 47: src = p.whl0; dst = p.whlf; n = 8192;    break;
    case 48: src = p.bhl0; dst = p.bhlf; n = 64;      break;
    case 49: src = p.clsw0; dst = p.clswf; n = 65536; break;
    case 50: src = p.clsb0; dst = p.clsbf; n = 4;     break;
    default: return;
  }
  for (int i = tid; i < n; i += 256) dst[i] = cvload(src, i, f);
}

// ================= init kernels =================
__global__ void k_scatter(Params p) {
  for (int e = threadIdx.x; e < E_; e += 256) {
    int s = p.eidx[e], d = p.eidx[E_ + e];
    atomicAdd(&p.Ascr[s * N_ + d], p.ewf[e]);
  }
}
__global__ void k_deg(Params p) {
  int j = threadIdx.x;
  float dg = 1.f;
  for (int i = 0; i < N_; ++i) dg += p.Ascr[i * N_ + j];
  p.dinvS[j] = rsqrtf(dg);
}
__global__ void k_ant(Params p) {
  int i = blockIdx.x, j = threadIdx.x;
  float a = p.Ascr[i * N_ + j] + (i == j ? 1.f : 0.f);
  p.AnT[j * N_ + i] = p.dinvS[i] * a * p.dinvS[j];
}
__global__ void k_uv(Params p) {
  int e = threadIdx.x; if (e >= 64) return;
  float uz = 0, vz = 0, ur = 0, vr = 0, uh = 0, vh = 0;
  for (int f = 0; f < 64; ++f) {
    float wz = p.wzlf[f * 64 + e], wr = p.wrlf[f * 64 + e], wh = p.whlf[f * 64 + e];
    uz += p.wzcf[f] * wz; vz += p.bzcf[f] * wz;
    ur += p.wrcf[f] * wr; vr += p.brcf[f] * wr;
    uh += p.whcf[f] * wh; vh += p.bhcf[f] * wh;
  }
  p.uvF[0 * 64 + e] = uz; p.uvF[1 * 64 + e] = vz + p.bzlf[e];
  p.uvF[2 * 64 + e] = ur; p.uvF[3 * 64 + e] = vr + p.brlf[e];
  p.uvF[4 * 64 + e] = uh; p.uvF[5 * 64 + e] = vh + p.bhlf[e];
}

// ================= main persistent kernel =================
__global__ void __launch_bounds__(256) dtgcn_main(Params p) {
  __shared__ __align__(16) u16 s_union[22016];  // phaseA: s_it[128*104]+s_xwT[64*136] / P3: j1,j2[128*72 ea] / P4: partials
  __shared__ __align__(16) u16 s_gwF[64 * 104];          // gw^T [e][k], K=96 (12 win + 64 h + pad)
  __shared__ __align__(16) u16 s_w1T[64 * 72], s_w2T[64 * 72];
  __shared__ __align__(16) u16 s_gzT[64 * 72], s_grT[64 * 72], s_ghT[64 * 72];
  __shared__ __align__(16) u16 s_antO1[16 * 264], s_antO2[16 * 264];  // split-bf16 A^T own rows
  __shared__ float s_msum[16 * 260];
  __shared__ __align__(16) u16 s_de1I[16 * 72], s_de2I[16 * 72];
  __shared__ __align__(16) u16 s_hbf[16 * 72];   // own h bf16 [i][k]
  __shared__ __align__(16) u16 s_dfhr[16 * 72];  // df (A) / h*r (P4)
  __shared__ float s_col[256], s_y[256], s_dinv[256], s_s[16];
  __shared__ float s_uv[384], s_gb[64], s_b1[64], s_b2[64];

  const int b = blockIdx.x & 15;
  const int wg = blockIdx.x >> 4;
  const int tid = threadIdx.x;
  const int lane = tid & 63;
  const int wv = tid >> 6;
  const int l = lane & 15;
  const int quad = lane >> 4;
  const int r0 = wg * 16;

  // ---- one-time LDS init ----
  for (int idx = tid; idx < 8192; idx += 256) {
    const int e = idx >> 7, k = idx & 127;
    if (k < 104) s_gwF[e * 104 + k] = (k < 76) ? f2b(p.gwf[k * 64 + e]) : (u16)0;
  }
  for (int idx = tid; idx < 4096; idx += 256) {
    const int ee = idx >> 6, ff = idx & 63;
    s_w1T[ee * 72 + ff] = p.w1h[ff * 64 + ee];
    s_w2T[ee * 72 + ff] = p.w2h[ff * 64 + ee];
    s_gzT[ee * 72 + ff] = f2b(p.wzlf[4096 + ff * 64 + ee]);
    s_grT[ee * 72 + ff] = f2b(p.wrlf[4096 + ff * 64 + ee]);
    s_ghT[ee * 72 + ff] = f2b(p.whlf[4096 + ff * 64 + ee]);
    // split-bf16 A^T (own 16 rows x all 256 i)
    const int j = idx >> 8, i = idx & 255;
    float a = p.AnT[(r0 + j) * N_ + i];
    u16 hi = f2b(a);
    s_antO1[j * 264 + i] = hi;
    s_antO2[j * 264 + i] = f2b(a - b2f(hi));
  }
  for (int idx = tid; idx < 16 * 260; idx += 256) s_msum[idx] = 0.f;
  for (int idx = tid; idx < 16 * 72; idx += 256) s_hbf[idx] = 0;
  for (int idx = tid; idx < 384; idx += 256) s_uv[idx] = p.uvF[idx];
  if (tid < 64) { s_gb[tid] = p.gbf[tid]; s_b1[tid] = p.b1f[tid]; s_b2[tid] = p.b2ff[tid]; }
  __syncthreads();

  u32*  de1g  = (u32*)p.de1 + (size_t)b * N_ * 32;
  u32*  de2g  = (u32*)p.de2 + (size_t)b * N_ * 32;
  u32*  hgpb  = p.hgp + (size_t)b * N_ * 32;
  float* hb   = p.h   + (size_t)b * N_ * 64;
  float* Msb  = p.Msum + (size_t)b * N_ * N_;
  float* degb = p.degsum + (size_t)b * N_;
  int* bar = p.bar + b * 64;
  int bcnt = 0;

  u16* s_it  = s_union;                 // [128][104]
  u16* s_xwT = s_union + 13312;         // [64][136]
  u16* s_j1  = s_union;                 // [128][72]
  u16* s_j2  = s_union + 9216;
  float* s_part = (float*)s_union;

  float hreg[4] = {0.f, 0.f, 0.f, 0.f};
  const int e = wv * 16 + l;            // this wave's column set

  for (int t = 0; t < T_; ++t) {
    // ---------- phase A: XW^T full (MFMA) ; df own (split-A MFMA) ; de ----------
    {
      f32x4 dfa = {0.f, 0.f, 0.f, 0.f};
      for (int half = 0; half < 2; ++half) {
        // stage It rows half*128..+127 into s_it [row][104]
        for (int idx = tid; idx < 2048; idx += 256) {
          const int row = idx >> 4, k = idx & 15;
          if (k < 12) {
            const int tx = t - (W_ - 1) + k;
            float v = (tx >= 0) ? p.xf[((size_t)b * N_ + half * 128 + row) * T_ + tx] : 0.f;
            s_it[row * 104 + k] = f2b(v);
          }
        }
        for (int idx = tid; idx < 4096; idx += 256) {
          const int row = idx >> 5, c = idx & 31;
          u32 v = gldu(&hgpb[(size_t)(half * 128 + row) * 32 + c]);
          *(u32*)&s_it[row * 104 + 12 + 2 * c] = v;
        }
        for (int idx = tid; idx < 1280; idx += 256) {
          const int row = idx / 10, c = idx - row * 10;
          *(u32*)&s_it[row * 104 + 76 + 2 * c] = 0;
        }
        __syncthreads();
        // XW^T[e][i] = sum_k gwF[e][k] It[i][k]  (each wave: 2 i-tiles x 4 e-tiles)
        #pragma unroll
        for (int nt2 = 0; nt2 < 2; ++nt2) {
          const int nt = wv * 2 + nt2;
          #pragma unroll
          for (int mt = 0; mt < 4; ++mt) {
            f32x4 acc = {0.f, 0.f, 0.f, 0.f};
            #pragma unroll
            for (int kt = 0; kt < 3; ++kt) {
              bf16x8 afr = ldfrag(&s_gwF[(mt * 16 + l) * 104 + kt * 32 + quad * 8]);
              bf16x8 bfr = ldfrag(&s_it[(nt * 16 + l) * 104 + kt * 32 + quad * 8]);
              acc = mfma16(afr, bfr, acc);
            }
            #pragma unroll
            for (int r = 0; r < 4; ++r)
              s_xwT[(mt * 16 + quad * 4 + r) * 136 + nt * 16 + l] = f2b(acc[r]);
          }
        }
        __syncthreads();
        // df[own j][e-tile wv] += A^T(own) @ XW^T  (split-bf16 A)
        #pragma unroll
        for (int kt = 0; kt < 4; ++kt) {
          const int ko = half * 128 + kt * 32 + quad * 8;
          bf16x8 bfr = ldfrag(&s_xwT[(wv * 16 + l) * 136 + kt * 32 + quad * 8]);
          dfa = mfma16(ldfrag(&s_antO1[l * 264 + ko]), bfr, dfa);
          dfa = mfma16(ldfrag(&s_antO2[l * 264 + ko]), bfr, dfa);
        }
        __syncthreads();   // before next half restages s_it/s_xwT
      }
      // bias + bf16 -> s_dfhr [j][e]
      #pragma unroll
      for (int r = 0; r < 4; ++r)
        s_dfhr[(quad * 4 + r) * 72 + e] = f2b(dfa[r] + s_gb[e]);
      __syncthreads();
      // de1/de2 (columns e)
      {
        f32x4 E1, E2;
        #pragma unroll
        for (int r = 0; r < 4; ++r) { E1[r] = s_b1[e]; E2[r] = s_b2[e]; }
        #pragma unroll
        for (int ks = 0; ks < 2; ++ks) {
          bf16x8 afr = ldfrag(&s_dfhr[l * 72 + ks * 32 + quad * 8]);
          E1 = mfma16(afr, ldfrag(&s_w1T[e * 72 + ks * 32 + quad * 8]), E1);
          E2 = mfma16(afr, ldfrag(&s_w2T[e * 72 + ks * 32 + quad * 8]), E2);
        }
        #pragma unroll
        for (int r = 0; r < 4; ++r) {
          s_de1I[(quad * 4 + r) * 72 + e] = f2b(ftanh(E1[r]));
          s_de2I[(quad * 4 + r) * 72 + e] = f2b(ftanh(E2[r]));
        }
      }
      __syncthreads();
      // publish de strips (packed u32)
      #pragma unroll
      for (int q = 0; q < 2; ++q) {
        const int idx = q * 256 + tid;
        const int row = idx >> 5, cp = idx & 31;
        u32 v1 = (u32)s_de1I[row * 72 + cp * 2] | ((u32)s_de1I[row * 72 + cp * 2 + 1] << 16);
        u32 v2 = (u32)s_de2I[row * 72 + cp * 2] | ((u32)s_de2I[row * 72 + cp * 2 + 1] << 16);
        gstu(&de1g[(size_t)(r0 + row) * 32 + cp], v1);
        gstu(&de2g[(size_t)(r0 + row) * 32 + cp], v2);
      }
    }
    bbar(bar, bcnt);  // B1: de exchange

    // ---------- P3: Et row strip via MFMA, Eh/Msum/deg ----------
    {
      const int sidx = t % S_;
      float* Ehr = p.Eh + (size_t)(b * S_ + sidx) * N_ * N_;
      s_col[tid] = 0.f;
      bf16x8 a1[2], a2[2];
      #pragma unroll
      for (int ks = 0; ks < 2; ++ks) {
        a1[ks] = ldfrag(&s_de1I[l * 72 + ks * 32 + quad * 8]);
        a2[ks] = ldfrag(&s_de2I[l * 72 + ks * 32 + quad * 8]);
      }
      for (int jh = 0; jh < 2; ++jh) {
        u32 t1[16], t2[16];
        #pragma unroll
        for (int q = 0; q < 16; ++q) {
          const int idx = q * 256 + tid;
          const int row = idx >> 5, cp = idx & 31;
          t1[q] = gldu(&de1g[(size_t)(jh * 128 + row) * 32 + cp]);
          t2[q] = gldu(&de2g[(size_t)(jh * 128 + row) * 32 + cp]);
        }
        __syncthreads();
        #pragma unroll
        for (int q = 0; q < 16; ++q) {
          const int idx = q * 256 + tid;
          const int row = idx >> 5, cp = idx & 31;
          *(u32*)&s_j1[row * 72 + cp * 2] = t1[q];
          *(u32*)&s_j2[row * 72 + cp * 2] = t2[q];
        }
        __syncthreads();
        #pragma unroll
        for (int jj2 = 0; jj2 < 2; ++jj2) {
          const int jloc = wv * 2 + jj2;
          f32x4 D1 = {0.f, 0.f, 0.f, 0.f}, D2 = {0.f, 0.f, 0.f, 0.f};
          #pragma unroll
          for (int ks = 0; ks < 2; ++ks) {
            bf16x8 bf2 = ldfrag(&s_j2[(jloc * 16 + l) * 72 + ks * 32 + quad * 8]);
            bf16x8 bf1 = ldfrag(&s_j1[(jloc * 16 + l) * 72 + ks * 32 + quad * 8]);
            D1 = mfma16(a1[ks], bf2, D1);
            D2 = mfma16(a2[ks], bf1, D2);
          }
          const int j = jh * 128 + jloc * 16 + l;
          float dc = 0.f;
          #pragma unroll
          for (int r = 0; r < 4; ++r) {
            const int i = quad * 4 + r;
            float d = ftanh(D1[r] - D2[r]);
            float eN = fmaxf(d, 0.f);
            float old = Ehr[(r0 + i) * N_ + j];
            float dd = eN - old;
            Ehr[(r0 + i) * N_ + j] = eN;
            float m = s_msum[i * 260 + j] + dd;
            s_msum[i * 260 + j] = m;
            gst(&Msb[(r0 + i) * N_ + j], m);
            dc += dd;
          }
          dc += __shfl_xor(dc, 16); dc += __shfl_xor(dc, 32);
          if (lane < 16) s_col[jh * 128 + jloc * 16 + lane] = dc;
        }
      }
      __syncthreads();
      atomicAdd(&degb[tid], s_col[tid]);
    }
    bbar(bar, bcnt);  // B2: Msum/deg exchange

    // ---------- P4: dinv/y, s, GRU, h publish ----------
    {
      const float cnt = (float)((t + 1 < S_) ? (t + 1) : S_);
      const float invc = 1.f / cnt;
      {
        float dg = 1.f + gld(&degb[tid]) * invc;
        float di = rsqrtf(dg);
        float xv = p.xf[((size_t)b * N_ + tid) * T_ + t];
        s_dinv[tid] = di;
        s_y[tid] = di * xv;
      }
      __syncthreads();
      {
        const int jj = tid & 15, c = tid >> 4;
        const int j = r0 + jj;
        float mv[16];
        #pragma unroll
        for (int k = 0; k < 16; ++k) mv[k] = gld(&Msb[(c * 16 + k) * N_ + j]);
        float part = 0.f;
        #pragma unroll
        for (int k = 0; k < 16; ++k) part += mv[k] * s_y[c * 16 + k];
        s_part[c * 16 + jj] = part;
      }
      __syncthreads();
      if (tid < 16) {
        float tot = 0.f;
        for (int k = 0; k < 16; ++k) tot += s_part[k * 16 + tid];
        const int j = r0 + tid;
        s_s[tid] = s_dinv[j] * (tot * invc + s_y[j]);
      }
      __syncthreads();
      float sv[4];
      #pragma unroll
      for (int r = 0; r < 4; ++r) sv[r] = s_s[quad * 4 + r];
      // z gate
      f32x4 az;
      #pragma unroll
      for (int r = 0; r < 4; ++r) az[r] = s_uv[0 * 64 + e] * sv[r] + s_uv[1 * 64 + e];
      #pragma unroll
      for (int ks = 0; ks < 2; ++ks) {
        bf16x8 afr = ldfrag(&s_hbf[l * 72 + ks * 32 + quad * 8]);
        az = mfma16(afr, ldfrag(&s_gzT[e * 72 + ks * 32 + quad * 8]), az);
      }
      float zz[4];
      #pragma unroll
      for (int r = 0; r < 4; ++r) zz[r] = fsigm(az[r]);
      // r gate
      f32x4 ar_;
      #pragma unroll
      for (int r = 0; r < 4; ++r) ar_[r] = s_uv[2 * 64 + e] * sv[r] + s_uv[3 * 64 + e];
      #pragma unroll
      for (int ks = 0; ks < 2; ++ks) {
        bf16x8 afr = ldfrag(&s_hbf[l * 72 + ks * 32 + quad * 8]);
        ar_ = mfma16(afr, ldfrag(&s_grT[e * 72 + ks * 32 + quad * 8]), ar_);
      }
      #pragma unroll
      for (int r = 0; r < 4; ++r)
        s_dfhr[(quad * 4 + r) * 72 + e] = f2b(hreg[r] * fsigm(ar_[r]));
      __syncthreads();
      // candidate
      f32x4 ah;
      #pragma unroll
      for (int r = 0; r < 4; ++r) ah[r] = s_uv[4 * 64 + e] * sv[r] + s_uv[5 * 64 + e];
      #pragma unroll
      for (int ks = 0; ks < 2; ++ks) {
        bf16x8 afr = ldfrag(&s_dfhr[l * 72 + ks * 32 + quad * 8]);
        ah = mfma16(afr, ldfrag(&s_ghT[e * 72 + ks * 32 + quad * 8]), ah);
      }
      #pragma unroll
      for (int r = 0; r < 4; ++r) {
        float ht = ftanh(ah[r]);
        hreg[r] = zz[r] * hreg[r] + (1.f - zz[r]) * ht;
      }
      #pragma unroll
      for (int r = 0; r < 4; ++r)
        s_hbf[(quad * 4 + r) * 72 + e] = f2b(hreg[r]);
      if (t == T_ - 1) {
        #pragma unroll
        for (int r = 0; r < 4; ++r)
          hb[(r0 + quad * 4 + r) * 64 + e] = hreg[r];
      }
      __syncthreads();
      // publish packed h strip for next step's phase A
      #pragma unroll
      for (int q = 0; q < 2; ++q) {
        const int idx = q * 256 + tid;
        const int row = idx >> 5, cp = idx & 31;
        u32 v = (u32)s_hbf[row * 72 + 2 * cp] | ((u32)s_hbf[row * 72 + 2 * cp + 1] << 16);
        gstu(&hgpb[(size_t)(r0 + row) * 32 + cp], v);
      }
    }
    bbar(bar, bcnt);  // B3: h exchange
  }
}

// ================= classifier =================
__global__ void k_cls(Params p) {
  __shared__ float red[256][4];
  const int b = blockIdx.x, i = threadIdx.x;
  const float* hr = p.h + ((size_t)b * N_ + i) * 64;
  const float* w = p.clswf + (size_t)i * 64 * 4;
  float a0 = 0, a1 = 0, a2 = 0, a3 = 0;
  for (int f = 0; f < 64; ++f) {
    float hv = hr[f];
    a0 += hv * w[f * 4 + 0]; a1 += hv * w[f * 4 + 1];
    a2 += hv * w[f * 4 + 2]; a3 += hv * w[f * 4 + 3];
  }
  red[i][0] = a0; red[i][1] = a1; red[i][2] = a2; red[i][3] = a3;
  __syncthreads();
  for (int st = 128; st > 0; st >>= 1) {
    if (i < st) {
      red[i][0] += red[i + st][0]; red[i][1] += red[i + st][1];
      red[i][2] += red[i + st][2]; red[i][3] += red[i + st][3];
    }
    __syncthreads();
  }
  if (i < 4) {
    float v = red[0][i] + p.clsbf[i];
    if (*p.flag) ((float*)p.out)[b * 4 + i] = v;
    else         ((u16*)p.out)[b * 4 + i] = f2b(v);
  }
}

extern "C" void kernel_launch(void* const* d_in, const int* in_sizes, int n_in,
                              void* d_out, int out_size, void* d_ws, size_t ws_size,
                              hipStream_t stream) {
  float* w = (float*)d_ws;
  size_t o = 0;
  auto alloc = [&](size_t n) { float* r = w + o; o += (n + 63) & ~(size_t)63; return r; };
  float* xf    = alloc(262144);
  float* ewf   = alloc(E_);
  float* gwf   = alloc(FG_ * 64);
  float* gbf   = alloc(64);
  float* b1f   = alloc(64);
  float* b2ff  = alloc(64);
  float* wzcf  = alloc(64); float* bzcf = alloc(64); float* wzlf = alloc(8192); float* bzlf = alloc(64);
  float* wrcf  = alloc(64); float* brcf = alloc(64); float* wrlf = alloc(8192); float* brlf = alloc(64);
  float* whcf  = alloc(64); float* bhcf = alloc(64); float* whlf = alloc(8192); float* bhlf = alloc(64);
  float* clswf = alloc(65536); float* clsbf = alloc(64);
  u16* w1h = (u16*)alloc(2048);
  u16* w2h = (u16*)alloc(2048);
  int* flag = (int*)alloc(64);
  float* AnT   = alloc(65536);
  float* dinvS = alloc(256);
  float* uvF   = alloc(384);
  float* de1   = alloc((size_t)B_ * N_ * 32);  // packed bf16 u32
  float* de2   = alloc((size_t)B_ * N_ * 32);
  const size_t zero_off = o;
  float* Ascr  = alloc((size_t)N_ * N_);
  float* h     = alloc((size_t)B_ * N_ * 64);
  u32*   hgp   = (u32*)alloc((size_t)B_ * N_ * 32);
  float* Msum  = alloc((size_t)B_ * N_ * N_);
  float* degs  = alloc((size_t)B_ * N_);
  int*   bar   = (int*)alloc(B_ * 64);
  float* Eh    = alloc((size_t)B_ * S_ * N_ * N_);
  if (ws_size < o * sizeof(float)) return;

  (void)hipMemsetAsync(w + zero_off, 0, (o - zero_off) * sizeof(float), stream);

  Params p;
  p.x0  = d_in[0];  p.ew0 = d_in[1];
  p.gw0 = d_in[2];  p.gb0 = d_in[3];
  p.w10 = d_in[4];  p.b10 = d_in[5];
  p.w20 = d_in[6];  p.b20 = d_in[7];
  p.wzc0 = d_in[8];  p.bzc0 = d_in[9];  p.wzl0 = d_in[10]; p.bzl0 = d_in[11];
  p.wrc0 = d_in[12]; p.brc0 = d_in[13]; p.wrl0 = d_in[14]; p.brl0 = d_in[15];
  p.whc0 = d_in[16]; p.bhc0 = d_in[17]; p.whl0 = d_in[18]; p.bhl0 = d_in[19];
  p.clsw0 = d_in[20]; p.clsb0 = d_in[21];
  p.eidx = (const int*)d_in[22];
  p.xf = xf; p.ewf = ewf; p.gwf = gwf; p.gbf = gbf; p.b1f = b1f; p.b2ff = b2ff;
  p.wzcf = wzcf; p.bzcf = bzcf; p.wzlf = wzlf; p.bzlf = bzlf;
  p.wrcf = wrcf; p.brcf = brcf; p.wrlf = wrlf; p.brlf = brlf;
  p.whcf = whcf; p.bhcf = bhcf; p.whlf = whlf; p.bhlf = bhlf;
  p.clswf = clswf; p.clsbf = clsbf; p.w1h = w1h; p.w2h = w2h;
  p.AnT = AnT; p.dinvS = dinvS; p.uvF = uvF; p.de1 = de1; p.de2 = de2;
  p.h = h; p.hgp = hgp; p.Msum = Msum; p.degsum = degs; p.Eh = Eh; p.Ascr = Ascr;
  p.bar = bar; p.flag = flag; p.out = d_out;

  k_detect<<<1, 64, 0, stream>>>(p);
  k_convert<<<53, 256, 0, stream>>>(p);
  k_scatter<<<1, 256, 0, stream>>>(p);
  k_deg<<<1, 256, 0, stream>>>(p);
  k_ant<<<N_, 256, 0, stream>>>(p);
  k_uv<<<1, 64, 0, stream>>>(p);

  void* args[] = { &p };
  hipError_t ce = hipLaunchCooperativeKernel((const void*)dtgcn_main,
                                             dim3(B_ * G_), dim3(256), args, 0, stream);
  if (ce != hipSuccess) {
    (void)hipGetLastError();
    dtgcn_main<<<dim3(B_ * G_), dim3(256), 0, stream>>>(p);
  }

  k_cls<<<B_, 256, 0, stream>>>(p);
}

// Round 9
// 1169.256 us; speedup vs baseline: 1.6962x; 1.6962x over previous
//
#include <hip/hip_runtime.h>
#include <hip/hip_bf16.h>

// DTGCN: B=16,N=256,T=64,W=12,H=64,ED=64,S=5,C=4,E=2048, FG=76
// R9 = R7 structure + targeted fixes:
//  - P1: own 16 rows XW via K=96 MFMA (h k0..63 in s_it, win k64..75), then
//    publishes XW^T packed-bf16 (transpose through LDS tile).
//  - P2: df = A^T@XW via split-bf16-A MFMA (16 mfma, no 256-b128 VALU loop).
//  - de/h exchanges bf16-packed. 3 fence-free barriers/step.

typedef unsigned short u16;
typedef unsigned int u32;
typedef __attribute__((ext_vector_type(8))) short bf16x8;
typedef __attribute__((ext_vector_type(4))) float f32x4;

#define B_ 16
#define N_ 256
#define T_ 64
#define W_ 12
#define S_ 5
#define E_ 2048
#define FG_ 76
#define G_ 16

__device__ __forceinline__ float b2f(u16 u) {
  union { u32 i; float f; } v; v.i = ((u32)u) << 16; return v.f;
}
__device__ __forceinline__ u16 f2b(float f) {
  union { float f; u32 i; } v; v.f = f;
  u32 x = v.i; x += 0x7fff + ((x >> 16) & 1); return (u16)(x >> 16);
}
__device__ __forceinline__ float ftanh(float x) {
  float e = __expf(-2.f * fabsf(x));
  float t = (1.f - e) / (1.f + e);
  return x < 0.f ? -t : t;
}
__device__ __forceinline__ float fsigm(float x) { return 1.f / (1.f + __expf(-x)); }
__device__ __forceinline__ float cvload(const void* p, int i, int f) {
  return f ? ((const float*)p)[i] : b2f(((const u16*)p)[i]);
}
__device__ __forceinline__ float gld(const float* p) {
  return __hip_atomic_load(p, __ATOMIC_RELAXED, __HIP_MEMORY_SCOPE_SYSTEM);
}
__device__ __forceinline__ void gst(float* p, float v) {
  __hip_atomic_store(p, v, __ATOMIC_RELAXED, __HIP_MEMORY_SCOPE_SYSTEM);
}
__device__ __forceinline__ u32 gldu(const u32* p) {
  return __hip_atomic_load(p, __ATOMIC_RELAXED, __HIP_MEMORY_SCOPE_SYSTEM);
}
__device__ __forceinline__ void gstu(u32* p, u32 v) {
  __hip_atomic_store(p, v, __ATOMIC_RELAXED, __HIP_MEMORY_SCOPE_SYSTEM);
}
__device__ __forceinline__ f32x4 mfma16(bf16x8 a, bf16x8 b, f32x4 c) {
  return __builtin_amdgcn_mfma_f32_16x16x32_bf16(a, b, c, 0, 0, 0);
}
__device__ __forceinline__ bf16x8 ldfrag(const u16* p) { return *(const bf16x8*)p; }

struct Params {
  const void *x0, *ew0, *gw0, *gb0, *w10, *b10, *w20, *b20;
  const void *wzc0, *bzc0, *wzl0, *bzl0, *wrc0, *brc0, *wrl0, *brl0;
  const void *whc0, *bhc0, *whl0, *bhl0, *clsw0, *clsb0;
  const int* eidx;
  float *xf, *ewf, *gwf, *gbf, *b1f, *b2ff;
  float *wzcf, *bzcf, *wzlf, *bzlf, *wrcf, *brcf, *wrlf, *brlf;
  float *whcf, *bhcf, *whlf, *bhlf, *clswf, *clsbf;
  u16 *w1h, *w2h;
  float *AnT, *dinvS, *uvF, *de1, *de2, *h, *Msum, *degsum, *Eh, *Ascr;
  u32 *xwt;
  int *bar, *flag;
  void* out;
};

__device__ __forceinline__ void bbar(int* ctr, int& cnt) {
  ++cnt;
  __syncthreads();
  if (threadIdx.x == 0) {
    __hip_atomic_fetch_add(ctr, 1, __ATOMIC_RELAXED, __HIP_MEMORY_SCOPE_SYSTEM);
    const int target = cnt * G_;
    while (__hip_atomic_load(ctr, __ATOMIC_RELAXED, __HIP_MEMORY_SCOPE_SYSTEM) < target)
      __builtin_amdgcn_s_sleep(1);
  }
  __syncthreads();
}

// ================= dtype detect + convert =================
__global__ void k_detect(Params p) {
  if (threadIdx.x == 0) {
    const u16* q = (const u16*)p.x0;
    int c = 0;
    for (int i = 0; i < 256; ++i) {
      int ex = (q[i] >> 7) & 0xff;
      c += (ex >= 110 && ex <= 135);
    }
    *p.flag = (c < 200) ? 1 : 0;
  }
}

__global__ void k_convert(Params p) {
  const int f = *p.flag;
  const int blk = blockIdx.x, tid = threadIdx.x;
  if (blk < 32) {
    const int base = blk * 8192;
    for (int i = tid; i < 8192; i += 256) p.xf[base + i] = cvload(p.x0, base + i, f);
    return;
  }
  if (blk == 51) { for (int i = tid; i < 4096; i += 256) p.w1h[i] = f ? f2b(((const float*)p.w10)[i]) : ((const u16*)p.w10)[i]; return; }
  if (blk == 52) { for (int i = tid; i < 4096; i += 256) p.w2h[i] = f ? f2b(((const float*)p.w20)[i]) : ((const u16*)p.w20)[i]; return; }
  const void* src = nullptr; float* dst = nullptr; int n = 0;
  switch (blk) {
    case 32: src = p.ew0;  dst = p.ewf;  n = E_;      break;
    case 33: src = p.gw0;  dst = p.gwf;  n = FG_ * 64; break;
    case 34: src = p.gb0;  dst = p.gbf;  n = 64;      break;
    case 35: src = p.b10;  dst = p.b1f;  n = 64;      break;
    case 36: src = p.b20;  dst = p.b2ff; n = 64;      break;
    case 37: src = p.wzc0; dst = p.wzcf; n = 64;      break;
    case 38: src = p.bzc0; dst = p.bzcf; n = 64;      break;
    case 39: src = p.wzl0; dst = p.wzlf; n = 8192;    break;
    case 40: src = p.bzl0; dst = p.bzlf; n = 64;      break;
    case 41: src = p.wrc0; dst = p.wrcf; n = 64;      break;
    case 42: src = p.brc0; dst = p.brcf; n = 64;      break;
    case 43: src = p.wrl0; dst = p.wrlf; n = 8192;    break;
    case 44: src = p.brl0; dst = p.brlf; n = 64;      break;
    case 45: src = p.whc0; dst = p.whcf; n = 64;      break;
    case 46: src = p.bhc0; dst = p.bhcf; n = 64;      break;
    case 47: src = p.whl0; dst = p.whlf; n = 8192;    break;
    case 48: src = p.bhl0; dst = p.bhlf; n = 64;      break;
    case 49: src = p.clsw0; dst = p.clswf; n = 65536; break;
    case 50: src = p.clsb0; dst = p.clsbf; n = 4;     break;
    default: return;
  }
  for (int i = tid; i < n; i += 256) dst[i] = cvload(src, i, f);
}

// ================= init kernels =================
__global__ void k_scatter(Params p) {
  for (int e = threadIdx.x; e < E_; e += 256) {
    int s = p.eidx[e], d = p.eidx[E_ + e];
    atomicAdd(&p.Ascr[s * N_ + d], p.ewf[e]);
  }
}
__global__ void k_deg(Params p) {
  int j = threadIdx.x;
  float dg = 1.f;
  for (int i = 0; i < N_; ++i) dg += p.Ascr[i * N_ + j];
  p.dinvS[j] = rsqrtf(dg);
}
__global__ void k_ant(Params p) {
  int i = blockIdx.x, j = threadIdx.x;
  float a = p.Ascr[i * N_ + j] + (i == j ? 1.f : 0.f);
  p.AnT[j * N_ + i] = p.dinvS[i] * a * p.dinvS[j];
}
__global__ void k_uv(Params p) {
  int e = threadIdx.x; if (e >= 64) return;
  float uz = 0, vz = 0, ur = 0, vr = 0, uh = 0, vh = 0;
  for (int f = 0; f < 64; ++f) {
    float wz = p.wzlf[f * 64 + e], wr = p.wrlf[f * 64 + e], wh = p.whlf[f * 64 + e];
    uz += p.wzcf[f] * wz; vz += p.bzcf[f] * wz;
    ur += p.wrcf[f] * wr; vr += p.brcf[f] * wr;
    uh += p.whcf[f] * wh; vh += p.bhcf[f] * wh;
  }
  p.uvF[0 * 64 + e] = uz; p.uvF[1 * 64 + e] = vz + p.bzlf[e];
  p.uvF[2 * 64 + e] = ur; p.uvF[3 * 64 + e] = vr + p.brlf[e];
  p.uvF[4 * 64 + e] = uh; p.uvF[5 * 64 + e] = vh + p.bhlf[e];
}

// ================= main persistent kernel =================
__global__ void __launch_bounds__(256) dtgcn_main(Params p) {
  __shared__ __align__(16) u16 s_union[22016];   // P2: xwT[64*264] / P3: j1,j2[128*72] / P4: partials
  __shared__ __align__(16) u16 s_gwF[64 * 104];  // gw^T [e][k]: k0..63=h-part, 64..75=win, pad
  __shared__ __align__(16) u16 s_w1T[64 * 72], s_w2T[64 * 72];
  __shared__ __align__(16) u16 s_gzT[64 * 72], s_grT[64 * 72], s_ghT[64 * 72];
  __shared__ __align__(16) u16 s_antO1[16 * 264], s_antO2[16 * 264];  // split-bf16 A^T own rows [j][i]
  __shared__ float s_msum[16 * 260];
  __shared__ __align__(16) u16 s_de1I[16 * 72], s_de2I[16 * 72];
  __shared__ __align__(16) u16 s_it[16 * 104];   // [i][k]: k0..63=h(bf16), 64..75=win, pad=0
  __shared__ __align__(16) u16 s_dfhr[16 * 72];  // P1 XW tile / P2 df / P4 h*r
  __shared__ float s_col[256], s_y[256], s_dinv[256], s_s[16];
  __shared__ float s_uv[384], s_gb[64], s_b1[64], s_b2[64];

  const int b = blockIdx.x & 15;
  const int wg = blockIdx.x >> 4;
  const int tid = threadIdx.x;
  const int lane = tid & 63;
  const int wv = tid >> 6;
  const int l = lane & 15;
  const int quad = lane >> 4;
  const int r0 = wg * 16;

  // ---- one-time LDS init ----
  for (int idx = tid; idx < 64 * 104; idx += 256) {
    const int ee = idx / 104, k = idx - ee * 104;
    u16 v = 0;
    if (k < 64) v = f2b(p.gwf[(12 + k) * 64 + ee]);        // h part
    else if (k < 76) v = f2b(p.gwf[(k - 64) * 64 + ee]);   // win part
    s_gwF[ee * 104 + k] = v;
  }
  for (int idx = tid; idx < 4096; idx += 256) {
    const int ee = idx >> 6, ff = idx & 63;
    s_w1T[ee * 72 + ff] = p.w1h[ff * 64 + ee];
    s_w2T[ee * 72 + ff] = p.w2h[ff * 64 + ee];
    s_gzT[ee * 72 + ff] = f2b(p.wzlf[4096 + ff * 64 + ee]);
    s_grT[ee * 72 + ff] = f2b(p.wrlf[4096 + ff * 64 + ee]);
    s_ghT[ee * 72 + ff] = f2b(p.whlf[4096 + ff * 64 + ee]);
    // split-bf16 A^T own rows: [j][i]
    const int j = idx >> 8, i = idx & 255;
    float a = p.AnT[(r0 + j) * N_ + i];
    u16 hi = f2b(a);
    s_antO1[j * 264 + i] = hi;
    s_antO2[j * 264 + i] = f2b(a - b2f(hi));
  }
  for (int idx = tid; idx < 16 * 260; idx += 256) s_msum[idx] = 0.f;
  for (int idx = tid; idx < 16 * 104; idx += 256) s_it[idx] = 0;
  for (int idx = tid; idx < 384; idx += 256) s_uv[idx] = p.uvF[idx];
  if (tid < 64) { s_gb[tid] = p.gbf[tid]; s_b1[tid] = p.b1f[tid]; s_b2[tid] = p.b2ff[tid]; }
  __syncthreads();

  u32*  de1g  = (u32*)p.de1 + (size_t)b * N_ * 32;
  u32*  de2g  = (u32*)p.de2 + (size_t)b * N_ * 32;
  u32*  xwtg  = p.xwt + (size_t)b * 64 * 128;     // XW^T packed [e][i/2]
  float* hb   = p.h   + (size_t)b * N_ * 64;
  float* Msb  = p.Msum + (size_t)b * N_ * N_;
  float* degb = p.degsum + (size_t)b * N_;
  int* bar = p.bar + b * 64;
  int bcnt = 0;

  u16* s_xwT = s_union;                 // [64][264] (P2)
  u16* s_j1  = s_union;                 // [128][72] (P3)
  u16* s_j2  = s_union + 9216;
  float* s_part = (float*)s_union;      // (P4)

  float hreg[4] = {0.f, 0.f, 0.f, 0.f};
  const int e = wv * 16 + l;

  for (int t = 0; t < T_; ++t) {
    // ---------- P1: XW own rows = [h|win] @ gw via K=96 MFMA; publish XW^T ----------
    {
      if (tid < 192) {
        const int row = tid / 12, k = tid - row * 12;
        const int tx = t - (W_ - 1) + k;
        float v = (tx >= 0) ? p.xf[((size_t)b * N_ + r0 + row) * T_ + tx] : 0.f;
        s_it[row * 104 + 64 + k] = f2b(v);
      }
      __syncthreads();
      f32x4 acc = {0.f, 0.f, 0.f, 0.f};
      #pragma unroll
      for (int kt = 0; kt < 3; ++kt) {
        bf16x8 afr = ldfrag(&s_it[l * 104 + kt * 32 + quad * 8]);
        bf16x8 bfr = ldfrag(&s_gwF[e * 104 + kt * 32 + quad * 8]);
        acc = mfma16(afr, bfr, acc);
      }
      // D[m=i][n=e]: i=quad*4+r (local), e=wv*16+l -> XW tile bf16 [i][e]
      #pragma unroll
      for (int r = 0; r < 4; ++r)
        s_dfhr[(quad * 4 + r) * 72 + e] = f2b(acc[r]);
      __syncthreads();
      // pack transpose: XWT[e][r0+ii], 512 u32
      #pragma unroll
      for (int q = 0; q < 2; ++q) {
        const int idx = q * 256 + tid;
        const int ee = idx >> 3, c = idx & 7;
        u32 v = (u32)s_dfhr[(2 * c) * 72 + ee] | ((u32)s_dfhr[(2 * c + 1) * 72 + ee] << 16);
        gstu(&xwtg[ee * 128 + (r0 >> 1) + c], v);
      }
    }
    bbar(bar, bcnt);  // B1: XW^T exchange

    // ---------- P2: df = A^T@XW (split-bf16 MFMA); de1/de2 ----------
    {
      u32 trg[32];
      #pragma unroll
      for (int q = 0; q < 32; ++q) trg[q] = gldu(&xwtg[q * 256 + tid]);
      #pragma unroll
      for (int q = 0; q < 32; ++q) {
        const int idx = q * 256 + tid;
        const int ee = idx >> 7, c = idx & 127;
        *(u32*)&s_xwT[ee * 264 + 2 * c] = trg[q];
      }
      __syncthreads();
      f32x4 dfa = {0.f, 0.f, 0.f, 0.f};
      #pragma unroll
      for (int kt = 0; kt < 8; ++kt) {
        const int ko = kt * 32 + quad * 8;
        bf16x8 bfr = ldfrag(&s_xwT[(wv * 16 + l) * 264 + ko]);
        dfa = mfma16(ldfrag(&s_antO1[l * 264 + ko]), bfr, dfa);
        dfa = mfma16(ldfrag(&s_antO2[l * 264 + ko]), bfr, dfa);
      }
      __syncthreads();  // s_xwT consumed (s_union reused by P3)
      // D[m=j][n=e]: df + bias -> s_dfhr [j][e]
      #pragma unroll
      for (int r = 0; r < 4; ++r)
        s_dfhr[(quad * 4 + r) * 72 + e] = f2b(dfa[r] + s_gb[e]);
      __syncthreads();
      // de1/de2 (columns e)
      {
        f32x4 E1, E2;
        #pragma unroll
        for (int r = 0; r < 4; ++r) { E1[r] = s_b1[e]; E2[r] = s_b2[e]; }
        #pragma unroll
        for (int ks = 0; ks < 2; ++ks) {
          bf16x8 afr = ldfrag(&s_dfhr[l * 72 + ks * 32 + quad * 8]);
          E1 = mfma16(afr, ldfrag(&s_w1T[e * 72 + ks * 32 + quad * 8]), E1);
          E2 = mfma16(afr, ldfrag(&s_w2T[e * 72 + ks * 32 + quad * 8]), E2);
        }
        #pragma unroll
        for (int r = 0; r < 4; ++r) {
          s_de1I[(quad * 4 + r) * 72 + e] = f2b(ftanh(E1[r]));
          s_de2I[(quad * 4 + r) * 72 + e] = f2b(ftanh(E2[r]));
        }
      }
      __syncthreads();
      // publish de strips (packed u32)
      #pragma unroll
      for (int q = 0; q < 2; ++q) {
        const int idx = q * 256 + tid;
        const int row = idx >> 5, cp = idx & 31;
        u32 v1 = (u32)s_de1I[row * 72 + cp * 2] | ((u32)s_de1I[row * 72 + cp * 2 + 1] << 16);
        u32 v2 = (u32)s_de2I[row * 72 + cp * 2] | ((u32)s_de2I[row * 72 + cp * 2 + 1] << 16);
        gstu(&de1g[(size_t)(r0 + row) * 32 + cp], v1);
        gstu(&de2g[(size_t)(r0 + row) * 32 + cp], v2);
      }
    }
    bbar(bar, bcnt);  // B2: de exchange

    // ---------- P3: Et row strip via MFMA, Eh/Msum/deg ----------
    {
      const int sidx = t % S_;
      float* Ehr = p.Eh + (size_t)(b * S_ + sidx) * N_ * N_;
      s_col[tid] = 0.f;
      bf16x8 a1[2], a2[2];
      #pragma unroll
      for (int ks = 0; ks < 2; ++ks) {
        a1[ks] = ldfrag(&s_de1I[l * 72 + ks * 32 + quad * 8]);
        a2[ks] = ldfrag(&s_de2I[l * 72 + ks * 32 + quad * 8]);
      }
      for (int jh = 0; jh < 2; ++jh) {
        u32 t1[16], t2[16];
        #pragma unroll
        for (int q = 0; q < 16; ++q) {
          const int idx = q * 256 + tid;
          const int row = idx >> 5, cp = idx & 31;
          t1[q] = gldu(&de1g[(size_t)(jh * 128 + row) * 32 + cp]);
          t2[q] = gldu(&de2g[(size_t)(jh * 128 + row) * 32 + cp]);
        }
        __syncthreads();
        #pragma unroll
        for (int q = 0; q < 16; ++q) {
          const int idx = q * 256 + tid;
          const int row = idx >> 5, cp = idx & 31;
          *(u32*)&s_j1[row * 72 + cp * 2] = t1[q];
          *(u32*)&s_j2[row * 72 + cp * 2] = t2[q];
        }
        __syncthreads();
        #pragma unroll
        for (int jj2 = 0; jj2 < 2; ++jj2) {
          const int jloc = wv * 2 + jj2;
          f32x4 D1 = {0.f, 0.f, 0.f, 0.f}, D2 = {0.f, 0.f, 0.f, 0.f};
          #pragma unroll
          for (int ks = 0; ks < 2; ++ks) {
            bf16x8 bf2 = ldfrag(&s_j2[(jloc * 16 + l) * 72 + ks * 32 + quad * 8]);
            bf16x8 bf1 = ldfrag(&s_j1[(jloc * 16 + l) * 72 + ks * 32 + quad * 8]);
            D1 = mfma16(a1[ks], bf2, D1);
            D2 = mfma16(a2[ks], bf1, D2);
          }
          const int j = jh * 128 + jloc * 16 + l;
          float dc = 0.f;
          #pragma unroll
          for (int r = 0; r < 4; ++r) {
            const int i = quad * 4 + r;
            float d = ftanh(D1[r] - D2[r]);
            float eN = fmaxf(d, 0.f);
            float old = Ehr[(r0 + i) * N_ + j];
            float dd = eN - old;
            Ehr[(r0 + i) * N_ + j] = eN;
            float m = s_msum[i * 260 + j] + dd;
            s_msum[i * 260 + j] = m;
            gst(&Msb[(r0 + i) * N_ + j], m);
            dc += dd;
          }
          dc += __shfl_xor(dc, 16); dc += __shfl_xor(dc, 32);
          if (lane < 16) s_col[jh * 128 + jloc * 16 + lane] = dc;
        }
      }
      __syncthreads();
      atomicAdd(&degb[tid], s_col[tid]);
    }
    bbar(bar, bcnt);  // B3: Msum/deg exchange

    // ---------- P4: dinv/y, s, GRU ----------
    {
      const float cnt = (float)((t + 1 < S_) ? (t + 1) : S_);
      const float invc = 1.f / cnt;
      {
        float dg = 1.f + gld(&degb[tid]) * invc;
        float di = rsqrtf(dg);
        float xv = p.xf[((size_t)b * N_ + tid) * T_ + t];
        s_dinv[tid] = di;
        s_y[tid] = di * xv;
      }
      __syncthreads();
      {
        const int jj = tid & 15, c = tid >> 4;
        const int j = r0 + jj;
        float mv[16];
        #pragma unroll
        for (int k = 0; k < 16; ++k) mv[k] = gld(&Msb[(c * 16 + k) * N_ + j]);
        float part = 0.f;
        #pragma unroll
        for (int k = 0; k < 16; ++k) part += mv[k] * s_y[c * 16 + k];
        s_part[c * 16 + jj] = part;
      }
      __syncthreads();
      if (tid < 16) {
        float tot = 0.f;
        for (int k = 0; k < 16; ++k) tot += s_part[k * 16 + tid];
        const int j = r0 + tid;
        s_s[tid] = s_dinv[j] * (tot * invc + s_y[j]);
      }
      __syncthreads();
      float sv[4];
      #pragma unroll
      for (int r = 0; r < 4; ++r) sv[r] = s_s[quad * 4 + r];
      // z gate
      f32x4 az;
      #pragma unroll
      for (int r = 0; r < 4; ++r) az[r] = s_uv[0 * 64 + e] * sv[r] + s_uv[1 * 64 + e];
      #pragma unroll
      for (int ks = 0; ks < 2; ++ks) {
        bf16x8 afr = ldfrag(&s_it[l * 104 + ks * 32 + quad * 8]);
        az = mfma16(afr, ldfrag(&s_gzT[e * 72 + ks * 32 + quad * 8]), az);
      }
      float zz[4];
      #pragma unroll
      for (int r = 0; r < 4; ++r) zz[r] = fsigm(az[r]);
      // r gate
      f32x4 ar_;
      #pragma unroll
      for (int r = 0; r < 4; ++r) ar_[r] = s_uv[2 * 64 + e] * sv[r] + s_uv[3 * 64 + e];
      #pragma unroll
      for (int ks = 0; ks < 2; ++ks) {
        bf16x8 afr = ldfrag(&s_it[l * 104 + ks * 32 + quad * 8]);
        ar_ = mfma16(afr, ldfrag(&s_grT[e * 72 + ks * 32 + quad * 8]), ar_);
      }
      #pragma unroll
      for (int r = 0; r < 4; ++r)
        s_dfhr[(quad * 4 + r) * 72 + e] = f2b(hreg[r] * fsigm(ar_[r]));
      __syncthreads();   // all s_it gate-reads done; h*r ready
      // candidate
      f32x4 ah;
      #pragma unroll
      for (int r = 0; r < 4; ++r) ah[r] = s_uv[4 * 64 + e] * sv[r] + s_uv[5 * 64 + e];
      #pragma unroll
      for (int ks = 0; ks < 2; ++ks) {
        bf16x8 afr = ldfrag(&s_dfhr[l * 72 + ks * 32 + quad * 8]);
        ah = mfma16(afr, ldfrag(&s_ghT[e * 72 + ks * 32 + quad * 8]), ah);
      }
      #pragma unroll
      for (int r = 0; r < 4; ++r) {
        float ht = ftanh(ah[r]);
        hreg[r] = zz[r] * hreg[r] + (1.f - zz[r]) * ht;
      }
      #pragma unroll
      for (int r = 0; r < 4; ++r)
        s_it[(quad * 4 + r) * 104 + e] = f2b(hreg[r]);   // h for next step
      if (t == T_ - 1) {
        #pragma unroll
        for (int r = 0; r < 4; ++r)
          hb[(r0 + quad * 4 + r) * 64 + e] = hreg[r];
      }
      __syncthreads();
    }
  }
}

// ================= classifier =================
__global__ void k_cls(Params p) {
  __shared__ float red[256][4];
  const int b = blockIdx.x, i = threadIdx.x;
  const float* hr = p.h + ((size_t)b * N_ + i) * 64;
  const float* w = p.clswf + (size_t)i * 64 * 4;
  float a0 = 0, a1 = 0, a2 = 0, a3 = 0;
  for (int f = 0; f < 64; ++f) {
    float hv = hr[f];
    a0 += hv * w[f * 4 + 0]; a1 += hv * w[f * 4 + 1];
    a2 += hv * w[f * 4 + 2]; a3 += hv * w[f * 4 + 3];
  }
  red[i][0] = a0; red[i][1] = a1; red[i][2] = a2; red[i][3] = a3;
  __syncthreads();
  for (int st = 128; st > 0; st >>= 1) {
    if (i < st) {
      red[i][0] += red[i + st][0]; red[i][1] += red[i + st][1];
      red[i][2] += red[i + st][2]; red[i][3] += red[i + st][3];
    }
    __syncthreads();
  }
  if (i < 4) {
    float v = red[0][i] + p.clsbf[i];
    if (*p.flag) ((float*)p.out)[b * 4 + i] = v;
    else         ((u16*)p.out)[b * 4 + i] = f2b(v);
  }
}

extern "C" void kernel_launch(void* const* d_in, const int* in_sizes, int n_in,
                              void* d_out, int out_size, void* d_ws, size_t ws_size,
                              hipStream_t stream) {
  float* w = (float*)d_ws;
  size_t o = 0;
  auto alloc = [&](size_t n) { float* r = w + o; o += (n + 63) & ~(size_t)63; return r; };
  float* xf    = alloc(262144);
  float* ewf   = alloc(E_);
  float* gwf   = alloc(FG_ * 64);
  float* gbf   = alloc(64);
  float* b1f   = alloc(64);
  float* b2ff  = alloc(64);
  float* wzcf  = alloc(64); float* bzcf = alloc(64); float* wzlf = alloc(8192); float* bzlf = alloc(64);
  float* wrcf  = alloc(64); float* brcf = alloc(64); float* wrlf = alloc(8192); float* brlf = alloc(64);
  float* whcf  = alloc(64); float* bhcf = alloc(64); float* whlf = alloc(8192); float* bhlf = alloc(64);
  float* clswf = alloc(65536); float* clsbf = alloc(64);
  u16* w1h = (u16*)alloc(2048);
  u16* w2h = (u16*)alloc(2048);
  int* flag = (int*)alloc(64);
  float* AnT   = alloc(65536);
  float* dinvS = alloc(256);
  float* uvF   = alloc(384);
  float* de1   = alloc((size_t)B_ * N_ * 32);   // packed bf16 u32
  float* de2   = alloc((size_t)B_ * N_ * 32);
  u32*   xwt   = (u32*)alloc((size_t)B_ * 64 * 128);
  const size_t zero_off = o;
  float* Ascr  = alloc((size_t)N_ * N_);
  float* h     = alloc((size_t)B_ * N_ * 64);
  float* Msum  = alloc((size_t)B_ * N_ * N_);
  float* degs  = alloc((size_t)B_ * N_);
  int*   bar   = (int*)alloc(B_ * 64);
  float* Eh    = alloc((size_t)B_ * S_ * N_ * N_);
  if (ws_size < o * sizeof(float)) return;

  (void)hipMemsetAsync(w + zero_off, 0, (o - zero_off) * sizeof(float), stream);

  Params p;
  p.x0  = d_in[0];  p.ew0 = d_in[1];
  p.gw0 = d_in[2];  p.gb0 = d_in[3];
  p.w10 = d_in[4];  p.b10 = d_in[5];
  p.w20 = d_in[6];  p.b20 = d_in[7];
  p.wzc0 = d_in[8];  p.bzc0 = d_in[9];  p.wzl0 = d_in[10]; p.bzl0 = d_in[11];
  p.wrc0 = d_in[12]; p.brc0 = d_in[13]; p.wrl0 = d_in[14]; p.brl0 = d_in[15];
  p.whc0 = d_in[16]; p.bhc0 = d_in[17]; p.whl0 = d_in[18]; p.bhl0 = d_in[19];
  p.clsw0 = d_in[20]; p.clsb0 = d_in[21];
  p.eidx = (const int*)d_in[22];
  p.xf = xf; p.ewf = ewf; p.gwf = gwf; p.gbf = gbf; p.b1f = b1f; p.b2ff = b2ff;
  p.wzcf = wzcf; p.bzcf = bzcf; p.wzlf = wzlf; p.bzlf = bzlf;
  p.wrcf = wrcf; p.brcf = brcf; p.wrlf = wrlf; p.brlf = brlf;
  p.whcf = whcf; p.bhcf = bhcf; p.whlf = whlf; p.bhlf = bhlf;
  p.clswf = clswf; p.clsbf = clsbf; p.w1h = w1h; p.w2h = w2h;
  p.AnT = AnT; p.dinvS = dinvS; p.uvF = uvF; p.de1 = de1; p.de2 = de2;
  p.h = h; p.Msum = Msum; p.degsum = degs; p.Eh = Eh; p.Ascr = Ascr;
  p.xwt = xwt; p.bar = bar; p.flag = flag; p.out = d_out;

  k_detect<<<1, 64, 0, stream>>>(p);
  k_convert<<<53, 256, 0, stream>>>(p);
  k_scatter<<<1, 256, 0, stream>>>(p);
  k_deg<<<1, 256, 0, stream>>>(p);
  k_ant<<<N_, 256, 0, stream>>>(p);
  k_uv<<<1, 64, 0, stream>>>(p);

  void* args[] = { &p };
  hipError_t ce = hipLaunchCooperativeKernel((const void*)dtgcn_main,
                                             dim3(B_ * G_), dim3(256), args, 0, stream);
  if (ce != hipSuccess) {
    (void)hipGetLastError();
    dtgcn_main<<<dim3(B_ * G_), dim3(256), 0, stream>>>(p);
  }

  k_cls<<<B_, 256, 0, stream>>>(p);
}

// Round 11
// 938.599 us; speedup vs baseline: 2.1131x; 1.2457x over previous
//
#include <hip/hip_runtime.h>
#include <hip/hip_bf16.h>

// DTGCN: B=16,N=256,T=64,W=12,H=64,ED=64,S=5,C=4,E=2048, FG=76
// R11 = R10 + fix: no 16x16x16_bf16 on gfx950 — K=80 contraction padded to
// K=96, 3x mfma_f32_16x16x32_bf16. P3 owns COLUMNS (Msum pure LDS);
// phase A: df = (A^T_own . It) @ gw; 3 fence-free barriers/step (de, deg, h).

typedef unsigned short u16;
typedef unsigned int u32;
typedef __attribute__((ext_vector_type(8))) short bf16x8;
typedef __attribute__((ext_vector_type(4))) float f32x4;

#define B_ 16
#define N_ 256
#define T_ 64
#define W_ 12
#define S_ 5
#define E_ 2048
#define FG_ 76
#define G_ 16

__device__ __forceinline__ float b2f(u16 u) {
  union { u32 i; float f; } v; v.i = ((u32)u) << 16; return v.f;
}
__device__ __forceinline__ u16 f2b(float f) {
  union { float f; u32 i; } v; v.f = f;
  u32 x = v.i; x += 0x7fff + ((x >> 16) & 1); return (u16)(x >> 16);
}
__device__ __forceinline__ float ftanh(float x) {
  float e = __expf(-2.f * fabsf(x));
  float t = (1.f - e) / (1.f + e);
  return x < 0.f ? -t : t;
}
__device__ __forceinline__ float fsigm(float x) { return 1.f / (1.f + __expf(-x)); }
__device__ __forceinline__ float cvload(const void* p, int i, int f) {
  return f ? ((const float*)p)[i] : b2f(((const u16*)p)[i]);
}
__device__ __forceinline__ float gld(const float* p) {
  return __hip_atomic_load(p, __ATOMIC_RELAXED, __HIP_MEMORY_SCOPE_SYSTEM);
}
__device__ __forceinline__ void gst(float* p, float v) {
  __hip_atomic_store(p, v, __ATOMIC_RELAXED, __HIP_MEMORY_SCOPE_SYSTEM);
}
__device__ __forceinline__ u32 gldu(const u32* p) {
  return __hip_atomic_load(p, __ATOMIC_RELAXED, __HIP_MEMORY_SCOPE_SYSTEM);
}
__device__ __forceinline__ void gstu(u32* p, u32 v) {
  __hip_atomic_store(p, v, __ATOMIC_RELAXED, __HIP_MEMORY_SCOPE_SYSTEM);
}
__device__ __forceinline__ f32x4 mfma16(bf16x8 a, bf16x8 b, f32x4 c) {
  return __builtin_amdgcn_mfma_f32_16x16x32_bf16(a, b, c, 0, 0, 0);
}
__device__ __forceinline__ bf16x8 ldfrag(const u16* p) { return *(const bf16x8*)p; }

struct Params {
  const void *x0, *ew0, *gw0, *gb0, *w10, *b10, *w20, *b20;
  const void *wzc0, *bzc0, *wzl0, *bzl0, *wrc0, *brc0, *wrl0, *brl0;
  const void *whc0, *bhc0, *whl0, *bhl0, *clsw0, *clsb0;
  const int* eidx;
  float *xf, *ewf, *gwf, *gbf, *b1f, *b2ff;
  float *wzcf, *bzcf, *wzlf, *bzlf, *wrcf, *brcf, *wrlf, *brlf;
  float *whcf, *bhcf, *whlf, *bhlf, *clswf, *clsbf;
  u16 *w1h, *w2h;
  float *AnT, *dinvS, *uvF, *de1, *de2, *h, *degsum, *Eh, *Ascr;
  u32 *xTp, *hgpT;
  int *bar, *flag;
  void* out;
};

__device__ __forceinline__ void bbar(int* ctr, int& cnt) {
  ++cnt;
  __syncthreads();
  if (threadIdx.x == 0) {
    __hip_atomic_fetch_add(ctr, 1, __ATOMIC_RELAXED, __HIP_MEMORY_SCOPE_SYSTEM);
    const int target = cnt * G_;
    while (__hip_atomic_load(ctr, __ATOMIC_RELAXED, __HIP_MEMORY_SCOPE_SYSTEM) < target)
      __builtin_amdgcn_s_sleep(1);
  }
  __syncthreads();
}

// ================= dtype detect + convert =================
__global__ void k_detect(Params p) {
  if (threadIdx.x == 0) {
    const u16* q = (const u16*)p.x0;
    int c = 0;
    for (int i = 0; i < 256; ++i) {
      int ex = (q[i] >> 7) & 0xff;
      c += (ex >= 110 && ex <= 135);
    }
    *p.flag = (c < 200) ? 1 : 0;
  }
}

__global__ void k_convert(Params p) {
  const int f = *p.flag;
  const int blk = blockIdx.x, tid = threadIdx.x;
  if (blk < 32) {
    const int base = blk * 8192;
    for (int i = tid; i < 8192; i += 256) p.xf[base + i] = cvload(p.x0, base + i, f);
    return;
  }
  if (blk == 51) { for (int i = tid; i < 4096; i += 256) p.w1h[i] = f ? f2b(((const float*)p.w10)[i]) : ((const u16*)p.w10)[i]; return; }
  if (blk == 52) { for (int i = tid; i < 4096; i += 256) p.w2h[i] = f ? f2b(((const float*)p.w20)[i]) : ((const u16*)p.w20)[i]; return; }
  const void* src = nullptr; float* dst = nullptr; int n = 0;
  switch (blk) {
    case 32: src = p.ew0;  dst = p.ewf;  n = E_;      break;
    case 33: src = p.gw0;  dst = p.gwf;  n = FG_ * 64; break;
    case 34: src = p.gb0;  dst = p.gbf;  n = 64;      break;
    case 35: src = p.b10;  dst = p.b1f;  n = 64;      break;
    case 36: src = p.b20;  dst = p.b2ff; n = 64;      break;
    case 37: src = p.wzc0; dst = p.wzcf; n = 64;      break;
    case 38: src = p.bzc0; dst = p.bzcf; n = 64;      break;
    case 39: src = p.wzl0; dst = p.wzlf; n = 8192;    break;
    case 40: src = p.bzl0; dst = p.bzlf; n = 64;      break;
    case 41: src = p.wrc0; dst = p.wrcf; n = 64;      break;
    case 42: src = p.brc0; dst = p.brcf; n = 64;      break;
    case 43: src = p.wrl0; dst = p.wrlf; n = 8192;    break;
    case 44: src = p.brl0; dst = p.brlf; n = 64;      break;
    case 45: src = p.whc0; dst = p.whcf; n = 64;      break;
    case 46: src = p.bhc0; dst = p.bhcf; n = 64;      break;
    case 47: src = p.whl0; dst = p.whlf; n = 8192;    break;
    case 48: src = p.bhl0; dst = p.bhlf; n = 64;      break;
    case 49: src = p.clsw0; dst = p.clswf; n = 65536; break;
    case 50: src = p.clsb0; dst = p.clsbf; n = 4;     break;
    default: return;
  }
  for (int i = tid; i < n; i += 256) dst[i] = cvload(src, i, f);
}

// x transpose: xTp[b][t][i/2] packed bf16
__global__ void k_xt(Params p) {
  __shared__ float tile[64 * 65];
  const int b = blockIdx.x, tid = threadIdx.x;
  for (int chunk = 0; chunk < 4; ++chunk) {
    __syncthreads();
    const int r = tid >> 2, tq = (tid & 3) * 16;
    #pragma unroll
    for (int q = 0; q < 16; ++q)
      tile[r * 65 + tq + q] = p.xf[((size_t)b * N_ + chunk * 64 + r) * T_ + tq + q];
    __syncthreads();
    #pragma unroll
    for (int q = 0; q < 8; ++q) {
      const int idx = q * 256 + tid;
      const int t = idx >> 5, c = idx & 31;
      u32 v = (u32)f2b(tile[(2 * c) * 65 + t]) | ((u32)f2b(tile[(2 * c + 1) * 65 + t]) << 16);
      p.xTp[(size_t)(b * 64 + t) * 128 + chunk * 32 + c] = v;
    }
  }
}

// ================= init kernels =================
__global__ void k_scatter(Params p) {
  for (int e = threadIdx.x; e < E_; e += 256) {
    int s = p.eidx[e], d = p.eidx[E_ + e];
    atomicAdd(&p.Ascr[s * N_ + d], p.ewf[e]);
  }
}
__global__ void k_deg(Params p) {
  int j = threadIdx.x;
  float dg = 1.f;
  for (int i = 0; i < N_; ++i) dg += p.Ascr[i * N_ + j];
  p.dinvS[j] = rsqrtf(dg);
}
__global__ void k_ant(Params p) {
  int i = blockIdx.x, j = threadIdx.x;
  float a = p.Ascr[i * N_ + j] + (i == j ? 1.f : 0.f);
  p.AnT[j * N_ + i] = p.dinvS[i] * a * p.dinvS[j];
}
__global__ void k_uv(Params p) {
  int e = threadIdx.x; if (e >= 64) return;
  float uz = 0, vz = 0, ur = 0, vr = 0, uh = 0, vh = 0;
  for (int f = 0; f < 64; ++f) {
    float wz = p.wzlf[f * 64 + e], wr = p.wrlf[f * 64 + e], wh = p.whlf[f * 64 + e];
    uz += p.wzcf[f] * wz; vz += p.bzcf[f] * wz;
    ur += p.wrcf[f] * wr; vr += p.brcf[f] * wr;
    uh += p.whcf[f] * wh; vh += p.bhcf[f] * wh;
  }
  p.uvF[0 * 64 + e] = uz; p.uvF[1 * 64 + e] = vz + p.bzlf[e];
  p.uvF[2 * 64 + e] = ur; p.uvF[3 * 64 + e] = vr + p.brlf[e];
  p.uvF[4 * 64 + e] = uh; p.uvF[5 * 64 + e] = vh + p.bhlf[e];
}

// ================= main persistent kernel =================
__global__ void __launch_bounds__(256) dtgcn_main(Params p) {
  __shared__ __align__(16) u16 s_union[21120];   // A: ItT[80][264] / P3: j1,j2[128][72] / P4: partials
  __shared__ __align__(16) u16 s_gwF[64 * 104];  // gw^T [e][k], k0..63=h, 64..75=win, pad to 96
  __shared__ __align__(16) u16 s_w1T[64 * 72], s_w2T[64 * 72];
  __shared__ __align__(16) u16 s_gzT[64 * 72], s_grT[64 * 72], s_ghT[64 * 72];
  __shared__ __align__(16) u16 s_antO1[16 * 264], s_antO2[16 * 264];  // split A^T own [j][i]
  __shared__ __align__(16) u16 s_m1[16 * 104];   // M1 [j][k] (k>=80 zero)
  __shared__ float s_msum[16 * 257];             // own Msum COLUMNS [j][i]
  __shared__ __align__(16) u16 s_de1I[16 * 72], s_de2I[16 * 72];
  __shared__ __align__(16) u16 s_hbf[16 * 72];   // own h bf16 [i][k]
  __shared__ __align__(16) u16 s_dfhr[16 * 72];  // df / h*r
  __shared__ float s_colv[16], s_degacc[16];
  __shared__ float s_y[256], s_dinv[256], s_s[16];
  __shared__ float s_uv[384], s_gb[64], s_b1[64], s_b2[64];

  const int b = blockIdx.x & 15;
  const int wg = blockIdx.x >> 4;
  const int tid = threadIdx.x;
  const int lane = tid & 63;
  const int wv = tid >> 6;
  const int l = lane & 15;
  const int quad = lane >> 4;
  const int r0 = wg * 16;

  // ---- one-time LDS init ----
  for (int idx = tid; idx < 64 * 104; idx += 256) {
    const int ee = idx / 104, k = idx - ee * 104;
    u16 v = 0;
    if (k < 64) v = f2b(p.gwf[(12 + k) * 64 + ee]);
    else if (k < 76) v = f2b(p.gwf[(k - 64) * 64 + ee]);
    s_gwF[ee * 104 + k] = v;
  }
  for (int idx = tid; idx < 4096; idx += 256) {
    const int ee = idx >> 6, ff = idx & 63;
    s_w1T[ee * 72 + ff] = p.w1h[ff * 64 + ee];
    s_w2T[ee * 72 + ff] = p.w2h[ff * 64 + ee];
    s_gzT[ee * 72 + ff] = f2b(p.wzlf[4096 + ff * 64 + ee]);
    s_grT[ee * 72 + ff] = f2b(p.wrlf[4096 + ff * 64 + ee]);
    s_ghT[ee * 72 + ff] = f2b(p.whlf[4096 + ff * 64 + ee]);
    const int j = idx >> 8, i = idx & 255;
    float a = p.AnT[(r0 + j) * N_ + i];
    u16 hi = f2b(a);
    s_antO1[j * 264 + i] = hi;
    s_antO2[j * 264 + i] = f2b(a - b2f(hi));
  }
  for (int idx = tid; idx < 16 * 257; idx += 256) s_msum[idx] = 0.f;
  for (int idx = tid; idx < 16 * 72; idx += 256) s_hbf[idx] = 0;
  for (int idx = tid; idx < 16 * 104; idx += 256) s_m1[idx] = 0;
  for (int idx = tid; idx < 384; idx += 256) s_uv[idx] = p.uvF[idx];
  if (tid < 64) { s_gb[tid] = p.gbf[tid]; s_b1[tid] = p.b1f[tid]; s_b2[tid] = p.b2ff[tid]; }
  if (tid < 16) s_degacc[tid] = 0.f;
  __syncthreads();

  u32*  de1g  = (u32*)p.de1 + (size_t)b * N_ * 32;
  u32*  de2g  = (u32*)p.de2 + (size_t)b * N_ * 32;
  u32*  hgpb  = p.hgpT + (size_t)b * 64 * 128;    // h^T packed [k][i/2]
  const u32* xTb = p.xTp + (size_t)b * 64 * 128;  // x^T packed [t][i/2]
  float* hb   = p.h + (size_t)b * N_ * 64;
  float* degb = p.degsum + (size_t)b * N_;
  int* bar = p.bar + b * 64;
  int bcnt = 0;

  u16* s_itT = s_union;                 // [80][264] (phase A)
  u16* s_j1  = s_union;                 // [128][72] (P3)
  u16* s_j2  = s_union + 9216;
  float* s_part = (float*)s_union;      // (P4)

  float hreg[4] = {0.f, 0.f, 0.f, 0.f};
  const int e = wv * 16 + l;

  for (int t = 0; t < T_; ++t) {
    // ---------- phase A: It^T stage; M1 = A^T_own @ It; df = M1 @ gw; de ----------
    {
      u32 th[32], tw[6];
      #pragma unroll
      for (int q = 0; q < 32; ++q) th[q] = gldu(&hgpb[q * 256 + tid]);
      #pragma unroll
      for (int q = 0; q < 6; ++q) {
        const int idx = q * 256 + tid;
        const int w2 = idx >> 7, c = idx & 127;
        const int tx = t - (W_ - 1) + w2;
        tw[q] = (tx >= 0) ? gldu(&xTb[(size_t)tx * 128 + c]) : 0u;
      }
      __syncthreads();
      #pragma unroll
      for (int q = 0; q < 32; ++q) {
        const int idx = q * 256 + tid;
        const int k = idx >> 7, c = idx & 127;
        *(u32*)&s_itT[k * 264 + 2 * c] = th[q];
      }
      #pragma unroll
      for (int q = 0; q < 6; ++q) {
        const int idx = q * 256 + tid;
        const int w2 = idx >> 7, c = idx & 127;
        *(u32*)&s_itT[(64 + w2) * 264 + 2 * c] = tw[q];
      }
      #pragma unroll
      for (int q = 0; q < 2; ++q) {     // pad rows 76..79
        const int idx = q * 256 + tid;
        const int k = 76 + (idx >> 7), c = idx & 127;
        *(u32*)&s_itT[k * 264 + 2 * c] = 0u;
      }
      __syncthreads();
      // M1[j][kk]: m=j(own16), n=kk (5 tiles of 16 over k=0..79), K=i (8 chunks)
      for (int nt = wv; nt < 5; nt += 4) {
        f32x4 acc = {0.f, 0.f, 0.f, 0.f};
        #pragma unroll
        for (int ch = 0; ch < 8; ++ch) {
          const int io = ch * 32 + quad * 8;
          bf16x8 bfr = ldfrag(&s_itT[(nt * 16 + l) * 264 + io]);
          acc = mfma16(ldfrag(&s_antO1[l * 264 + io]), bfr, acc);
          acc = mfma16(ldfrag(&s_antO2[l * 264 + io]), bfr, acc);
        }
        #pragma unroll
        for (int r = 0; r < 4; ++r)
          s_m1[(quad * 4 + r) * 104 + nt * 16 + l] = f2b(acc[r]);
      }
      __syncthreads();
      // df[j][e] = M1 @ gw + gb : K=96 (3x K32; k>=80 is zero on both sides)
      {
        f32x4 dfa = {0.f, 0.f, 0.f, 0.f};
        #pragma unroll
        for (int ks = 0; ks < 3; ++ks) {
          bf16x8 afr = ldfrag(&s_m1[l * 104 + ks * 32 + quad * 8]);
          dfa = mfma16(afr, ldfrag(&s_gwF[e * 104 + ks * 32 + quad * 8]), dfa);
        }
        #pragma unroll
        for (int r = 0; r < 4; ++r)
          s_dfhr[(quad * 4 + r) * 72 + e] = f2b(dfa[r] + s_gb[e]);
      }
      __syncthreads();
      // de1/de2 (columns e)
      {
        f32x4 E1, E2;
        #pragma unroll
        for (int r = 0; r < 4; ++r) { E1[r] = s_b1[e]; E2[r] = s_b2[e]; }
        #pragma unroll
        for (int ks = 0; ks < 2; ++ks) {
          bf16x8 afr = ldfrag(&s_dfhr[l * 72 + ks * 32 + quad * 8]);
          E1 = mfma16(afr, ldfrag(&s_w1T[e * 72 + ks * 32 + quad * 8]), E1);
          E2 = mfma16(afr, ldfrag(&s_w2T[e * 72 + ks * 32 + quad * 8]), E2);
        }
        #pragma unroll
        for (int r = 0; r < 4; ++r) {
          s_de1I[(quad * 4 + r) * 72 + e] = f2b(ftanh(E1[r]));
          s_de2I[(quad * 4 + r) * 72 + e] = f2b(ftanh(E2[r]));
        }
      }
      __syncthreads();
      // publish own de strips
      #pragma unroll
      for (int q = 0; q < 2; ++q) {
        const int idx = q * 256 + tid;
        const int row = idx >> 5, cp = idx & 31;
        u32 v1 = (u32)s_de1I[row * 72 + cp * 2] | ((u32)s_de1I[row * 72 + cp * 2 + 1] << 16);
        u32 v2 = (u32)s_de2I[row * 72 + cp * 2] | ((u32)s_de2I[row * 72 + cp * 2 + 1] << 16);
        gstu(&de1g[(size_t)(r0 + row) * 32 + cp], v1);
        gstu(&de2g[(size_t)(r0 + row) * 32 + cp], v2);
      }
    }
    bbar(bar, bcnt);  // B1: de exchange

    // ---------- P3: Et COLUMN strip (all i x own j), Eh/Msum(LDS)/deg ----------
    {
      const int sidx = t % S_;
      float* Ehc = p.Eh + (size_t)(b * S_ + sidx) * N_ * N_;  // [j][i] layout, own j rows
      if (tid < 16) s_colv[tid] = 0.f;
      float dcacc = 0.f;
      bf16x8 b1f_[2], b2f_[2];
      #pragma unroll
      for (int ks = 0; ks < 2; ++ks) {
        b1f_[ks] = ldfrag(&s_de1I[l * 72 + ks * 32 + quad * 8]);
        b2f_[ks] = ldfrag(&s_de2I[l * 72 + ks * 32 + quad * 8]);
      }
      for (int jh = 0; jh < 2; ++jh) {
        u32 t1[16], t2[16];
        #pragma unroll
        for (int q = 0; q < 16; ++q) {
          const int idx = q * 256 + tid;
          const int row = idx >> 5, cp = idx & 31;
          t1[q] = gldu(&de1g[(size_t)(jh * 128 + row) * 32 + cp]);
          t2[q] = gldu(&de2g[(size_t)(jh * 128 + row) * 32 + cp]);
        }
        __syncthreads();
        #pragma unroll
        for (int q = 0; q < 16; ++q) {
          const int idx = q * 256 + tid;
          const int row = idx >> 5, cp = idx & 31;
          *(u32*)&s_j1[row * 72 + cp * 2] = t1[q];
          *(u32*)&s_j2[row * 72 + cp * 2] = t2[q];
        }
        __syncthreads();
        #pragma unroll
        for (int mt2 = 0; mt2 < 2; ++mt2) {
          const int mt = wv * 2 + mt2;          // i-tile within half (0..7)
          f32x4 D1 = {0.f, 0.f, 0.f, 0.f}, D2 = {0.f, 0.f, 0.f, 0.f};
          #pragma unroll
          for (int ks = 0; ks < 2; ++ks) {
            bf16x8 af1 = ldfrag(&s_j1[(mt * 16 + l) * 72 + ks * 32 + quad * 8]);
            bf16x8 af2 = ldfrag(&s_j2[(mt * 16 + l) * 72 + ks * 32 + quad * 8]);
            D1 = mfma16(af1, b2f_[ks], D1);     // de1_i . de2_j
            D2 = mfma16(af2, b1f_[ks], D2);     // de2_i . de1_j
          }
          // D[m][n]: m=i_local=quad*4+r, n=j_local=l
          #pragma unroll
          for (int r = 0; r < 4; ++r) {
            const int i = jh * 128 + mt * 16 + quad * 4 + r;
            float d = ftanh(D1[r] - D2[r]);
            float eN = fmaxf(d, 0.f);
            float old = Ehc[(r0 + l) * N_ + i];
            float dd = eN - old;
            Ehc[(r0 + l) * N_ + i] = eN;
            s_msum[l * 257 + i] += dd;
            dcacc += dd;
          }
        }
      }
      dcacc += __shfl_xor(dcacc, 16);
      dcacc += __shfl_xor(dcacc, 32);
      if (lane < 16) atomicAdd(&s_colv[lane], dcacc);
      __syncthreads();
      if (tid < 16) {
        float nd = s_degacc[tid] + s_colv[tid];
        s_degacc[tid] = nd;
        gst(&degb[r0 + tid], nd);   // sole owner: absolute value
      }
    }
    bbar(bar, bcnt);  // B2: deg exchange (16 floats/WG)

    // ---------- P4: dinv/y, s (Msum from LDS), GRU, h publish ----------
    {
      const float cnt = (float)((t + 1 < S_) ? (t + 1) : S_);
      const float invc = 1.f / cnt;
      {
        float dg = 1.f + gld(&degb[tid]) * invc;
        float di = rsqrtf(dg);
        float xv = p.xf[((size_t)b * N_ + tid) * T_ + t];
        s_dinv[tid] = di;
        s_y[tid] = di * xv;
      }
      __syncthreads();
      {
        const int jl = tid & 15, c = tid >> 4;
        float part = 0.f;
        #pragma unroll
        for (int k = 0; k < 16; ++k)
          part += s_msum[jl * 257 + c * 16 + k] * s_y[c * 16 + k];
        s_part[c * 16 + jl] = part;
      }
      __syncthreads();
      if (tid < 16) {
        float tot = 0.f;
        for (int k = 0; k < 16; ++k) tot += s_part[k * 16 + tid];
        const int j = r0 + tid;
        s_s[tid] = s_dinv[j] * (tot * invc + s_y[j]);
      }
      __syncthreads();
      float sv[4];
      #pragma unroll
      for (int r = 0; r < 4; ++r) sv[r] = s_s[quad * 4 + r];
      // z gate
      f32x4 az;
      #pragma unroll
      for (int r = 0; r < 4; ++r) az[r] = s_uv[0 * 64 + e] * sv[r] + s_uv[1 * 64 + e];
      #pragma unroll
      for (int ks = 0; ks < 2; ++ks) {
        bf16x8 afr = ldfrag(&s_hbf[l * 72 + ks * 32 + quad * 8]);
        az = mfma16(afr, ldfrag(&s_gzT[e * 72 + ks * 32 + quad * 8]), az);
      }
      float zz[4];
      #pragma unroll
      for (int r = 0; r < 4; ++r) zz[r] = fsigm(az[r]);
      // r gate
      f32x4 ar_;
      #pragma unroll
      for (int r = 0; r < 4; ++r) ar_[r] = s_uv[2 * 64 + e] * sv[r] + s_uv[3 * 64 + e];
      #pragma unroll
      for (int ks = 0; ks < 2; ++ks) {
        bf16x8 afr = ldfrag(&s_hbf[l * 72 + ks * 32 + quad * 8]);
        ar_ = mfma16(afr, ldfrag(&s_grT[e * 72 + ks * 32 + quad * 8]), ar_);
      }
      #pragma unroll
      for (int r = 0; r < 4; ++r)
        s_dfhr[(quad * 4 + r) * 72 + e] = f2b(hreg[r] * fsigm(ar_[r]));
      __syncthreads();
      // candidate
      f32x4 ah;
      #pragma unroll
      for (int r = 0; r < 4; ++r) ah[r] = s_uv[4 * 64 + e] * sv[r] + s_uv[5 * 64 + e];
      #pragma unroll
      for (int ks = 0; ks < 2; ++ks) {
        bf16x8 afr = ldfrag(&s_dfhr[l * 72 + ks * 32 + quad * 8]);
        ah = mfma16(afr, ldfrag(&s_ghT[e * 72 + ks * 32 + quad * 8]), ah);
      }
      #pragma unroll
      for (int r = 0; r < 4; ++r) {
        float ht = ftanh(ah[r]);
        hreg[r] = zz[r] * hreg[r] + (1.f - zz[r]) * ht;
      }
      #pragma unroll
      for (int r = 0; r < 4; ++r)
        s_hbf[(quad * 4 + r) * 72 + e] = f2b(hreg[r]);
      if (t == T_ - 1) {
        #pragma unroll
        for (int r = 0; r < 4; ++r)
          hb[(r0 + quad * 4 + r) * 64 + e] = hreg[r];
      }
      __syncthreads();
      // publish h^T strip: hgpT[k][own i/2]
      #pragma unroll
      for (int q = 0; q < 2; ++q) {
        const int idx = q * 256 + tid;
        const int k = idx >> 3, c = idx & 7;
        u32 v = (u32)s_hbf[(2 * c) * 72 + k] | ((u32)s_hbf[(2 * c + 1) * 72 + k] << 16);
        gstu(&hgpb[(size_t)k * 128 + (r0 >> 1) + c], v);
      }
    }
    bbar(bar, bcnt);  // B3: h exchange
  }
}

// ================= classifier =================
__global__ void k_cls(Params p) {
  __shared__ float red[256][4];
  const int b = blockIdx.x, i = threadIdx.x;
  const float* hr = p.h + ((size_t)b * N_ + i) * 64;
  const float* w = p.clswf + (size_t)i * 64 * 4;
  float a0 = 0, a1 = 0, a2 = 0, a3 = 0;
  for (int f = 0; f < 64; ++f) {
    float hv = hr[f];
    a0 += hv * w[f * 4 + 0]; a1 += hv * w[f * 4 + 1];
    a2 += hv * w[f * 4 + 2]; a3 += hv * w[f * 4 + 3];
  }
  red[i][0] = a0; red[i][1] = a1; red[i][2] = a2; red[i][3] = a3;
  __syncthreads();
  for (int st = 128; st > 0; st >>= 1) {
    if (i < st) {
      red[i][0] += red[i + st][0]; red[i][1] += red[i + st][1];
      red[i][2] += red[i + st][2]; red[i][3] += red[i + st][3];
    }
    __syncthreads();
  }
  if (i < 4) {
    float v = red[0][i] + p.clsbf[i];
    if (*p.flag) ((float*)p.out)[b * 4 + i] = v;
    else         ((u16*)p.out)[b * 4 + i] = f2b(v);
  }
}

extern "C" void kernel_launch(void* const* d_in, const int* in_sizes, int n_in,
                              void* d_out, int out_size, void* d_ws, size_t ws_size,
                              hipStream_t stream) {
  float* w = (float*)d_ws;
  size_t o = 0;
  auto alloc = [&](size_t n) { float* r = w + o; o += (n + 63) & ~(size_t)63; return r; };
  float* xf    = alloc(262144);
  float* ewf   = alloc(E_);
  float* gwf   = alloc(FG_ * 64);
  float* gbf   = alloc(64);
  float* b1f   = alloc(64);
  float* b2ff  = alloc(64);
  float* wzcf  = alloc(64); float* bzcf = alloc(64); float* wzlf = alloc(8192); float* bzlf = alloc(64);
  float* wrcf  = alloc(64); float* brcf = alloc(64); float* wrlf = alloc(8192); float* brlf = alloc(64);
  float* whcf  = alloc(64); float* bhcf = alloc(64); float* whlf = alloc(8192); float* bhlf = alloc(64);
  float* clswf = alloc(65536); float* clsbf = alloc(64);
  u16* w1h = (u16*)alloc(2048);
  u16* w2h = (u16*)alloc(2048);
  int* flag = (int*)alloc(64);
  float* AnT   = alloc(65536);
  float* dinvS = alloc(256);
  float* uvF   = alloc(384);
  float* de1   = alloc((size_t)B_ * N_ * 32);
  float* de2   = alloc((size_t)B_ * N_ * 32);
  u32*   xTp   = (u32*)alloc((size_t)B_ * 64 * 128);
  const size_t zero_off = o;
  float* Ascr  = alloc((size_t)N_ * N_);
  float* h     = alloc((size_t)B_ * N_ * 64);
  u32*   hgpT  = (u32*)alloc((size_t)B_ * 64 * 128);
  float* degs  = alloc((size_t)B_ * N_);
  int*   bar   = (int*)alloc(B_ * 64);
  float* Eh    = alloc((size_t)B_ * S_ * N_ * N_);
  if (ws_size < o * sizeof(float)) return;

  (void)hipMemsetAsync(w + zero_off, 0, (o - zero_off) * sizeof(float), stream);

  Params p;
  p.x0  = d_in[0];  p.ew0 = d_in[1];
  p.gw0 = d_in[2];  p.gb0 = d_in[3];
  p.w10 = d_in[4];  p.b10 = d_in[5];
  p.w20 = d_in[6];  p.b20 = d_in[7];
  p.wzc0 = d_in[8];  p.bzc0 = d_in[9];  p.wzl0 = d_in[10]; p.bzl0 = d_in[11];
  p.wrc0 = d_in[12]; p.brc0 = d_in[13]; p.wrl0 = d_in[14]; p.brl0 = d_in[15];
  p.whc0 = d_in[16]; p.bhc0 = d_in[17]; p.whl0 = d_in[18]; p.bhl0 = d_in[19];
  p.clsw0 = d_in[20]; p.clsb0 = d_in[21];
  p.eidx = (const int*)d_in[22];
  p.xf = xf; p.ewf = ewf; p.gwf = gwf; p.gbf = gbf; p.b1f = b1f; p.b2ff = b2ff;
  p.wzcf = wzcf; p.bzcf = bzcf; p.wzlf = wzlf; p.bzlf = bzlf;
  p.wrcf = wrcf; p.brcf = brcf; p.wrlf = wrlf; p.brlf = brlf;
  p.whcf = whcf; p.bhcf = bhcf; p.whlf = whlf; p.bhlf = bhlf;
  p.clswf = clswf; p.clsbf = clsbf; p.w1h = w1h; p.w2h = w2h;
  p.AnT = AnT; p.dinvS = dinvS; p.uvF = uvF; p.de1 = de1; p.de2 = de2;
  p.h = h; p.degsum = degs; p.Eh = Eh; p.Ascr = Ascr;
  p.xTp = xTp; p.hgpT = hgpT; p.bar = bar; p.flag = flag; p.out = d_out;

  k_detect<<<1, 64, 0, stream>>>(p);
  k_convert<<<53, 256, 0, stream>>>(p);
  k_xt<<<B_, 256, 0, stream>>>(p);
  k_scatter<<<1, 256, 0, stream>>>(p);
  k_deg<<<1, 256, 0, stream>>>(p);
  k_ant<<<N_, 256, 0, stream>>>(p);
  k_uv<<<1, 64, 0, stream>>>(p);

  void* args[] = { &p };
  hipError_t ce = hipLaunchCooperativeKernel((const void*)dtgcn_main,
                                             dim3(B_ * G_), dim3(256), args, 0, stream);
  if (ce != hipSuccess) {
    (void)hipGetLastError();
    dtgcn_main<<<dim3(B_ * G_), dim3(256), 0, stream>>>(p);
  }

  k_cls<<<B_, 256, 0, stream>>>(p);
}